// Round 1
// baseline (7432.293 us; speedup 1.0000x reference)
//
#include <hip/hip_runtime.h>
#include <hip/hip_bf16.h>
#include <math.h>

#define B_ 4
#define S_ 4096
#define D_ 2048
#define DC_ 512
#define DFF_ 8192

typedef __attribute__((ext_vector_type(8))) __bf16 bf16x8;
typedef __attribute__((ext_vector_type(4))) float f32x4;

__device__ __forceinline__ float gelu_exact(float x) {
    return 0.5f * x * (1.0f + erff(x * 0.70710678118654752f));
}

__device__ __forceinline__ unsigned short f2bf_bits(float f) {
    __hip_bfloat16 h = __float2bfloat16(f);
    return *reinterpret_cast<unsigned short*>(&h);
}

#define GLD16(gptr, lptr) \
    __builtin_amdgcn_global_load_lds( \
        (__attribute__((address_space(1))) void*)(gptr), \
        (__attribute__((address_space(3))) void*)(lptr), 16, 0, 0)

// ---------------- pooled mean (deterministic 2-stage) ----------------
__global__ void pool_partial_k(const float* __restrict__ hidden, float* __restrict__ pp) {
    int d = blockIdx.x * 256 + threadIdx.x;
    int sc = blockIdx.y;
    int b = blockIdx.z;
    const float* base = hidden + ((size_t)b * S_ + (size_t)sc * 512) * D_ + d;
    float s = 0.f;
    #pragma unroll 4
    for (int i = 0; i < 512; ++i) s += base[(size_t)i * D_];
    pp[((size_t)sc * B_ + b) * D_ + d] = s;
}

__global__ void pool_reduce_k(const float* __restrict__ pp, float* __restrict__ pooled) {
    int tid = blockIdx.x * 256 + threadIdx.x;   // B_*D_ threads
    int b = tid >> 11;
    int d = tid & (D_ - 1);
    float s = 0.f;
    for (int sc = 0; sc < 8; ++sc) s += pp[((size_t)sc * B_ + b) * D_ + d];
    pooled[tid] = s * (1.0f / (float)S_);
}

// ---------------- router logits (fp32, one wave per token) ----------------
__global__ __launch_bounds__(256) void logits_k(const float* __restrict__ hidden,
                                                const float* __restrict__ rw,
                                                const float* __restrict__ rb,
                                                float* __restrict__ logits) {
    int tok = blockIdx.x * 4 + (threadIdx.x >> 6);
    int lane = threadIdx.x & 63;
    const float4* row = (const float4*)(hidden + (size_t)tok * D_);
    const float4* w4 = (const float4*)rw;
    float s = 0.f;
    #pragma unroll
    for (int i = 0; i < 8; ++i) {
        float4 v = row[i * 64 + lane];
        float4 w = w4[i * 64 + lane];
        s += (v.x * w.x + v.y * w.y) + (v.z * w.z + v.w * w.w);
    }
    #pragma unroll
    for (int off = 32; off > 0; off >>= 1) s += __shfl_down(s, off, 64);
    if (lane == 0) logits[tok] = s + rb[0];
}

// ---------------- complexity head ----------------
__global__ void head1_k(const float* __restrict__ pooled, const float* __restrict__ w1,
                        const float* __restrict__ b1, float* __restrict__ ch) {
    int j = blockIdx.x * 256 + threadIdx.x;   // 0..B_*DC_-1
    int b = j >> 9, c = j & (DC_ - 1);
    float acc = 0.f;
    for (int i = 0; i < D_; ++i) acc += pooled[b * D_ + i] * w1[(size_t)i * DC_ + c];
    ch[j] = gelu_exact(acc + b1[c]);
}

__global__ void head2_k(const float* __restrict__ ch, const float* __restrict__ w2,
                        const float* __restrict__ b2, int* __restrict__ kbuf) {
    __shared__ float red[4];
    int t = threadIdx.x;
    int b = t >> 6, lane = t & 63;
    float acc = 0.f;
    #pragma unroll
    for (int i = 0; i < 8; ++i) acc += ch[b * DC_ + i * 64 + lane] * w2[i * 64 + lane];
    #pragma unroll
    for (int off = 32; off > 0; off >>= 1) acc += __shfl_down(acc, off, 64);
    if (lane == 0) {
        float z = acc + b2[0];
        float cx = 1.f / (1.f + expf(-z));
        red[b] = 0.25f + cx * 0.75f;
    }
    __syncthreads();
    if (t == 0) {
        float cap = ((red[0] + red[1]) + (red[2] + red[3])) * 0.25f;
        int kk = (int)((double)cap * (double)S_);
        if (kk < 0) kk = 0;
        if (kk > S_) kk = S_;
        kbuf[0] = kk;
    }
}

// ---------------- per-batch top-k select (radix select + compaction) ----------------
__global__ __launch_bounds__(256) void select_k(const float* __restrict__ logits,
                                                const int* __restrict__ kbuf,
                                                int* __restrict__ gidx,
                                                float* __restrict__ gwt) {
    int b = blockIdx.x;
    int t = threadIdx.x;
    int k = kbuf[0];
    __shared__ float slog[S_];
    __shared__ unsigned su[S_];
    __shared__ int hist[256];
    __shared__ unsigned sprefix;
    __shared__ int srem;
    __shared__ int sg[256], se[256];

    for (int i = t; i < S_; i += 256) {
        float f = logits[b * S_ + i];
        slog[i] = f;
        unsigned ub = __float_as_uint(f);
        su[i] = (ub & 0x80000000u) ? ~ub : (ub | 0x80000000u);
    }
    if (t == 0) { sprefix = 0u; srem = k; }
    __syncthreads();

    for (int round = 0; round < 4; ++round) {
        int shift = 24 - round * 8;
        hist[t] = 0;
        __syncthreads();
        unsigned pref = sprefix;
        unsigned pmask = (round == 0) ? 0u : ~((1u << (shift + 8)) - 1u);
        for (int i = t; i < S_; i += 256) {
            unsigned u = su[i];
            if ((u & pmask) == (pref & pmask))
                atomicAdd(&hist[(u >> shift) & 255], 1);
        }
        __syncthreads();
        if (t == 0) {
            int rem = srem, run = 0;
            for (int v = 255; v >= 0; --v) {
                int h = hist[v];
                if (run + h >= rem) {
                    srem = rem - run;
                    sprefix = pref | ((unsigned)v << shift);
                    break;
                }
                run += h;
            }
        }
        __syncthreads();
    }
    unsigned T = sprefix;
    int need_eq = srem;

    int base = t * 16;
    int local_gt = 0, local_eq = 0;
    #pragma unroll
    for (int i = 0; i < 16; ++i) {
        unsigned u = su[base + i];
        local_gt += (u > T);
        local_eq += (u == T);
    }
    sg[t] = local_gt; se[t] = local_eq;
    __syncthreads();
    for (int o = 1; o < 256; o <<= 1) {
        int vg = (t >= o) ? sg[t - o] : 0;
        int ve = (t >= o) ? se[t - o] : 0;
        __syncthreads();
        sg[t] += vg; se[t] += ve;
        __syncthreads();
    }
    int gt_excl = sg[t] - local_gt;
    int eq_excl = se[t] - local_eq;
    int total_gt = sg[255];

    int gpos = gt_excl, epos = eq_excl;
    for (int i = 0; i < 16; ++i) {
        int s = base + i;
        unsigned u = su[s];
        int pos = -1;
        if (u > T) pos = gpos++;
        else if (u == T) { if (epos < need_eq) pos = total_gt + epos; epos++; }
        if (pos >= 0) {
            gidx[b * k + pos] = b * S_ + s;
            gwt[b * k + pos] = 1.f / (1.f + expf(-slog[s]));
        }
    }
}

// ---------------- gather selected rows -> packed bf16 A ----------------
__global__ void gather_k(const float* __restrict__ hidden, const int* __restrict__ gidx,
                         const int* __restrict__ kbuf, __hip_bfloat16* __restrict__ Ag) {
    int tid = blockIdx.x * 256 + threadIdx.x;  // B_*S_*(D_/4) worst case
    int m = tid >> 9, c4 = tid & 511;
    int M = B_ * kbuf[0];
    if (m >= M) return;
    int row = gidx[m];
    float4 v = ((const float4*)(hidden + (size_t)row * D_))[c4];
    ushort4 o;
    o.x = f2bf_bits(v.x); o.y = f2bf_bits(v.y); o.z = f2bf_bits(v.z); o.w = f2bf_bits(v.w);
    ((ushort4*)Ag)[tid] = o;
}

// ---------------- fp32 -> bf16 transpose (for B^T GEMM layout) ----------------
__global__ void transpose_cvt_k(const float* __restrict__ in, __hip_bfloat16* __restrict__ out,
                                int R, int C) {
    __shared__ float tile[32][33];
    int r0 = blockIdx.y * 32, c0 = blockIdx.x * 32;
    int tx = threadIdx.x, ty = threadIdx.y;
    #pragma unroll
    for (int i = 0; i < 32; i += 8)
        tile[ty + i][tx] = in[(size_t)(r0 + ty + i) * C + (c0 + tx)];
    __syncthreads();
    #pragma unroll
    for (int i = 0; i < 32; i += 8)
        out[(size_t)(c0 + ty + i) * R + (r0 + tx)] = __float2bfloat16(tile[tx][ty + i]);
}

// ---------------- GEMM1: H = gelu(Ag @ w1 + b1), bf16 MFMA ----------------
__global__ __launch_bounds__(256) void gemm1_k(const __hip_bfloat16* __restrict__ A,
                                               const __hip_bfloat16* __restrict__ BT,  // [DFF_][D_]
                                               const float* __restrict__ bias,
                                               __hip_bfloat16* __restrict__ H,
                                               const int* __restrict__ kbuf,
                                               int cBase, int CH) {
    int M = B_ * kbuf[0];
    int m0 = blockIdx.x * 128;
    if (m0 >= M) return;
    int nt = blockIdx.y;
    int n0g = cBase + nt * 128;
    __shared__ __align__(16) __hip_bfloat16 As[128 * 32];
    __shared__ __align__(16) __hip_bfloat16 Bs[128 * 32];
    int t = threadIdx.x;
    int lane = t & 63, wave = t >> 6;
    int wm = (wave & 1) * 64, wn = (wave >> 1) * 64;
    f32x4 acc[4][4] = {};

    int ar0 = t >> 2,            ac0 = (t & 3) * 8;
    int ar1 = (256 + t) >> 2,    ac1 = ((256 + t) & 3) * 8;
    int am0 = m0 + ar0; if (am0 >= M) am0 = M - 1;
    int am1 = m0 + ar1; if (am1 >= M) am1 = M - 1;
    const __hip_bfloat16* aP0 = A + (size_t)am0 * D_ + ac0;
    const __hip_bfloat16* aP1 = A + (size_t)am1 * D_ + ac1;
    const __hip_bfloat16* bP0 = BT + (size_t)(n0g + ar0) * D_ + ac0;
    const __hip_bfloat16* bP1 = BT + (size_t)(n0g + ar1) * D_ + ac1;
    unsigned ldsOff0 = (unsigned)(wave * 64) * 16u;
    unsigned ldsOff1 = 4096u + (unsigned)(wave * 64) * 16u;

    for (int kk = 0; kk < D_; kk += 32) {
        GLD16(aP0 + kk, (char*)As + ldsOff0);
        GLD16(aP1 + kk, (char*)As + ldsOff1);
        GLD16(bP0 + kk, (char*)Bs + ldsOff0);
        GLD16(bP1 + kk, (char*)Bs + ldsOff1);
        __syncthreads();
        bf16x8 af[4], bfr[4];
        #pragma unroll
        for (int i = 0; i < 4; ++i)
            af[i] = *(const bf16x8*)(As + (wm + i * 16 + (lane & 15)) * 32 + (lane >> 4) * 8);
        #pragma unroll
        for (int j = 0; j < 4; ++j)
            bfr[j] = *(const bf16x8*)(Bs + (wn + j * 16 + (lane & 15)) * 32 + (lane >> 4) * 8);
        #pragma unroll
        for (int i = 0; i < 4; ++i)
            #pragma unroll
            for (int j = 0; j < 4; ++j)
                acc[i][j] = __builtin_amdgcn_mfma_f32_16x16x32_bf16(af[i], bfr[j], acc[i][j], 0, 0, 0);
        __syncthreads();
    }

    int qrow = (lane >> 4) * 4, qcol = lane & 15;
    for (int i = 0; i < 4; ++i)
        for (int j = 0; j < 4; ++j) {
            int cc = wn + j * 16 + qcol;
            float bv = bias[n0g + cc];
            #pragma unroll
            for (int r = 0; r < 4; ++r) {
                int mm = m0 + wm + i * 16 + qrow + r;
                if (mm < M) {
                    float v = acc[i][j][r] + bv;
                    H[(size_t)mm * CH + (nt * 128 + cc)] = __float2bfloat16(gelu_exact(v));
                }
            }
        }
}

// ---------------- GEMM2: out[gidx[m]] += gwt[m] * (H @ w2 + b2) ----------------
__global__ __launch_bounds__(256) void gemm2_k(const __hip_bfloat16* __restrict__ A,   // H [*][CH]
                                               const __hip_bfloat16* __restrict__ BT,  // [D_][DFF_]
                                               const float* __restrict__ bias,
                                               const int* __restrict__ gidx,
                                               const float* __restrict__ gwt,
                                               float* __restrict__ out,
                                               const int* __restrict__ kbuf,
                                               int cBase, int CH, int first) {
    int M = B_ * kbuf[0];
    int m0 = blockIdx.x * 128;
    if (m0 >= M) return;
    int nt = blockIdx.y;
    int n0 = nt * 128;
    __shared__ __align__(16) __hip_bfloat16 As[128 * 32];
    __shared__ __align__(16) __hip_bfloat16 Bs[128 * 32];
    int t = threadIdx.x;
    int lane = t & 63, wave = t >> 6;
    int wm = (wave & 1) * 64, wn = (wave >> 1) * 64;
    f32x4 acc[4][4] = {};

    int ar0 = t >> 2,            ac0 = (t & 3) * 8;
    int ar1 = (256 + t) >> 2,    ac1 = ((256 + t) & 3) * 8;
    int am0 = m0 + ar0; if (am0 >= M) am0 = M - 1;
    int am1 = m0 + ar1; if (am1 >= M) am1 = M - 1;
    const __hip_bfloat16* aP0 = A + (size_t)am0 * CH + ac0;
    const __hip_bfloat16* aP1 = A + (size_t)am1 * CH + ac1;
    const __hip_bfloat16* bP0 = BT + (size_t)(n0 + ar0) * DFF_ + cBase + ac0;
    const __hip_bfloat16* bP1 = BT + (size_t)(n0 + ar1) * DFF_ + cBase + ac1;
    unsigned ldsOff0 = (unsigned)(wave * 64) * 16u;
    unsigned ldsOff1 = 4096u + (unsigned)(wave * 64) * 16u;

    for (int kk = 0; kk < CH; kk += 32) {
        GLD16(aP0 + kk, (char*)As + ldsOff0);
        GLD16(aP1 + kk, (char*)As + ldsOff1);
        GLD16(bP0 + kk, (char*)Bs + ldsOff0);
        GLD16(bP1 + kk, (char*)Bs + ldsOff1);
        __syncthreads();
        bf16x8 af[4], bfr[4];
        #pragma unroll
        for (int i = 0; i < 4; ++i)
            af[i] = *(const bf16x8*)(As + (wm + i * 16 + (lane & 15)) * 32 + (lane >> 4) * 8);
        #pragma unroll
        for (int j = 0; j < 4; ++j)
            bfr[j] = *(const bf16x8*)(Bs + (wn + j * 16 + (lane & 15)) * 32 + (lane >> 4) * 8);
        #pragma unroll
        for (int i = 0; i < 4; ++i)
            #pragma unroll
            for (int j = 0; j < 4; ++j)
                acc[i][j] = __builtin_amdgcn_mfma_f32_16x16x32_bf16(af[i], bfr[j], acc[i][j], 0, 0, 0);
        __syncthreads();
    }

    int qrow = (lane >> 4) * 4, qcol = lane & 15;
    for (int i = 0; i < 4; ++i)
        for (int j = 0; j < 4; ++j) {
            int cc = wn + j * 16 + qcol;
            int nglob = n0 + cc;
            float bv = bias[nglob];
            #pragma unroll
            for (int r = 0; r < 4; ++r) {
                int mm = m0 + wm + i * 16 + qrow + r;
                if (mm < M) {
                    int grow = gidx[mm];
                    float wgt = gwt[mm];
                    float v = acc[i][j][r];
                    if (first) v += bv;
                    out[(size_t)grow * D_ + nglob] += wgt * v;
                }
            }
        }
}

extern "C" void kernel_launch(void* const* d_in, const int* in_sizes, int n_in,
                              void* d_out, int out_size, void* d_ws, size_t ws_size,
                              hipStream_t stream) {
    (void)in_sizes; (void)n_in;
    const float* hidden = (const float*)d_in[0];
    const float* rw  = (const float*)d_in[1];
    const float* rb  = (const float*)d_in[2];
    const float* cw1 = (const float*)d_in[3];
    const float* cb1 = (const float*)d_in[4];
    const float* cw2 = (const float*)d_in[5];
    const float* cb2 = (const float*)d_in[6];
    const float* fw1 = (const float*)d_in[7];
    const float* fb1 = (const float*)d_in[8];
    const float* fw2 = (const float*)d_in[9];
    const float* fb2 = (const float*)d_in[10];

    char* ws = (char*)d_ws;
    size_t off = 0;
    auto alloc = [&](size_t bytes) {
        size_t r = (off + 255) & ~(size_t)255;
        off = r + bytes;
        return r;
    };
    size_t o_logits = alloc((size_t)B_ * S_ * 4);
    size_t o_pp     = alloc((size_t)8 * B_ * D_ * 4);
    size_t o_pooled = alloc((size_t)B_ * D_ * 4);
    size_t o_ch     = alloc((size_t)B_ * DC_ * 4);
    size_t o_k      = alloc(256);
    size_t o_gidx   = alloc((size_t)B_ * S_ * 4);
    size_t o_gwt    = alloc((size_t)B_ * S_ * 4);
    size_t o_w1T    = alloc((size_t)D_ * DFF_ * 2);
    size_t o_w2T    = alloc((size_t)D_ * DFF_ * 2);
    size_t o_Ag     = alloc((size_t)B_ * S_ * D_ * 2);
    size_t base     = (off + 255) & ~(size_t)255;
    int CH = DFF_;
    while (CH > 128 && base + (size_t)B_ * S_ * CH * 2 > ws_size) CH >>= 1;
    size_t o_H = alloc((size_t)B_ * S_ * CH * 2);

    float* logits = (float*)(ws + o_logits);
    float* pp     = (float*)(ws + o_pp);
    float* pooled = (float*)(ws + o_pooled);
    float* ch     = (float*)(ws + o_ch);
    int*   kbuf   = (int*)(ws + o_k);
    int*   gidx   = (int*)(ws + o_gidx);
    float* gwt    = (float*)(ws + o_gwt);
    __hip_bfloat16* w1T = (__hip_bfloat16*)(ws + o_w1T);
    __hip_bfloat16* w2T = (__hip_bfloat16*)(ws + o_w2T);
    __hip_bfloat16* Ag  = (__hip_bfloat16*)(ws + o_Ag);
    __hip_bfloat16* H   = (__hip_bfloat16*)(ws + o_H);
    float* out = (float*)d_out;

    pool_partial_k<<<dim3(D_ / 256, 8, B_), 256, 0, stream>>>(hidden, pp);
    pool_reduce_k<<<dim3(B_ * D_ / 256), 256, 0, stream>>>(pp, pooled);
    logits_k<<<dim3(B_ * S_ / 4), 256, 0, stream>>>(hidden, rw, rb, logits);
    head1_k<<<dim3(B_ * DC_ / 256), 256, 0, stream>>>(pooled, cw1, cb1, ch);
    head2_k<<<dim3(1), 256, 0, stream>>>(ch, cw2, cb2, kbuf);
    select_k<<<dim3(B_), 256, 0, stream>>>(logits, kbuf, gidx, gwt);
    gather_k<<<dim3(B_ * S_ * (D_ / 4) / 256), 256, 0, stream>>>(hidden, gidx, kbuf, Ag);
    transpose_cvt_k<<<dim3(DFF_ / 32, D_ / 32), dim3(32, 8), 0, stream>>>(fw1, w1T, D_, DFF_);
    transpose_cvt_k<<<dim3(D_ / 32, DFF_ / 32), dim3(32, 8), 0, stream>>>(fw2, w2T, DFF_, D_);
    hipMemcpyAsync(d_out, (const void*)hidden, (size_t)out_size * 4,
                   hipMemcpyDeviceToDevice, stream);

    int nch = DFF_ / CH;
    for (int c = 0; c < nch; ++c) {
        gemm1_k<<<dim3(B_ * S_ / 128, CH / 128), 256, 0, stream>>>(
            Ag, w1T, fb1, H, kbuf, c * CH, CH);
        gemm2_k<<<dim3(B_ * S_ / 128, D_ / 128), 256, 0, stream>>>(
            H, w2T, fb2, gidx, gwt, out, kbuf, c * CH, CH, c == 0);
    }
}

// Round 2
// 1777.704 us; speedup vs baseline: 4.1808x; 4.1808x over previous
//
#include <hip/hip_runtime.h>
#include <hip/hip_bf16.h>
#include <math.h>

#define B_ 4
#define S_ 4096
#define D_ 2048
#define DC_ 512
#define DFF_ 8192

typedef __attribute__((ext_vector_type(8))) __bf16 bf16x8;
typedef __attribute__((ext_vector_type(4))) float f32x4;

__device__ __forceinline__ float gelu_exact(float x) {
    return 0.5f * x * (1.0f + erff(x * 0.70710678118654752f));
}

__device__ __forceinline__ unsigned short f2bf_bits(float f) {
    __hip_bfloat16 h = __float2bfloat16(f);
    return *reinterpret_cast<unsigned short*>(&h);
}

#define GLD16(gptr, lptr) \
    __builtin_amdgcn_global_load_lds( \
        (__attribute__((address_space(1))) void*)(gptr), \
        (__attribute__((address_space(3))) void*)(lptr), 16, 0, 0)

// ---------------- pooled mean (deterministic 2-stage) ----------------
__global__ void pool_partial_k(const float* __restrict__ hidden, float* __restrict__ pp) {
    int d = blockIdx.x * 256 + threadIdx.x;
    int sc = blockIdx.y;
    int b = blockIdx.z;
    const float* base = hidden + ((size_t)b * S_ + (size_t)sc * 512) * D_ + d;
    float s = 0.f;
    #pragma unroll 4
    for (int i = 0; i < 512; ++i) s += base[(size_t)i * D_];
    pp[((size_t)sc * B_ + b) * D_ + d] = s;
}

__global__ void pool_reduce_k(const float* __restrict__ pp, float* __restrict__ pooled) {
    int tid = blockIdx.x * 256 + threadIdx.x;   // B_*D_ threads
    int b = tid >> 11;
    int d = tid & (D_ - 1);
    float s = 0.f;
    for (int sc = 0; sc < 8; ++sc) s += pp[((size_t)sc * B_ + b) * D_ + d];
    pooled[tid] = s * (1.0f / (float)S_);
}

// ---------------- router logits (fp32, one wave per token) ----------------
__global__ __launch_bounds__(256) void logits_k(const float* __restrict__ hidden,
                                                const float* __restrict__ rw,
                                                const float* __restrict__ rb,
                                                float* __restrict__ logits) {
    int tok = blockIdx.x * 4 + (threadIdx.x >> 6);
    int lane = threadIdx.x & 63;
    const float4* row = (const float4*)(hidden + (size_t)tok * D_);
    const float4* w4 = (const float4*)rw;
    float s = 0.f;
    #pragma unroll
    for (int i = 0; i < 8; ++i) {
        float4 v = row[i * 64 + lane];
        float4 w = w4[i * 64 + lane];
        s += (v.x * w.x + v.y * w.y) + (v.z * w.z + v.w * w.w);
    }
    #pragma unroll
    for (int off = 32; off > 0; off >>= 1) s += __shfl_down(s, off, 64);
    if (lane == 0) logits[tok] = s + rb[0];
}

// ---------------- complexity head ----------------
__global__ void head1_k(const float* __restrict__ pooled, const float* __restrict__ w1,
                        const float* __restrict__ b1, float* __restrict__ ch) {
    int j = blockIdx.x * 256 + threadIdx.x;   // 0..B_*DC_-1
    int b = j >> 9, c = j & (DC_ - 1);
    float acc = 0.f;
    for (int i = 0; i < D_; ++i) acc += pooled[b * D_ + i] * w1[(size_t)i * DC_ + c];
    ch[j] = gelu_exact(acc + b1[c]);
}

__global__ void head2_k(const float* __restrict__ ch, const float* __restrict__ w2,
                        const float* __restrict__ b2, int* __restrict__ kbuf) {
    __shared__ float red[4];
    int t = threadIdx.x;
    int b = t >> 6, lane = t & 63;
    float acc = 0.f;
    #pragma unroll
    for (int i = 0; i < 8; ++i) acc += ch[b * DC_ + i * 64 + lane] * w2[i * 64 + lane];
    #pragma unroll
    for (int off = 32; off > 0; off >>= 1) acc += __shfl_down(acc, off, 64);
    if (lane == 0) {
        float z = acc + b2[0];
        float cx = 1.f / (1.f + expf(-z));
        red[b] = 0.25f + cx * 0.75f;
    }
    __syncthreads();
    if (t == 0) {
        float cap = ((red[0] + red[1]) + (red[2] + red[3])) * 0.25f;
        int kk = (int)((double)cap * (double)S_);
        if (kk < 0) kk = 0;
        if (kk > S_) kk = S_;
        kbuf[0] = kk;
    }
}

// ---------------- per-batch top-k select (radix select + compaction) ----------------
__global__ __launch_bounds__(256) void select_k(const float* __restrict__ logits,
                                                const int* __restrict__ kbuf,
                                                int* __restrict__ gidx,
                                                float* __restrict__ gwt) {
    int b = blockIdx.x;
    int t = threadIdx.x;
    int k = kbuf[0];
    __shared__ float slog[S_];
    __shared__ unsigned su[S_];
    __shared__ int hist[256];
    __shared__ unsigned sprefix;
    __shared__ int srem;
    __shared__ int sg[256], se[256];

    for (int i = t; i < S_; i += 256) {
        float f = logits[b * S_ + i];
        slog[i] = f;
        unsigned ub = __float_as_uint(f);
        su[i] = (ub & 0x80000000u) ? ~ub : (ub | 0x80000000u);
    }
    if (t == 0) { sprefix = 0u; srem = k; }
    __syncthreads();

    for (int round = 0; round < 4; ++round) {
        int shift = 24 - round * 8;
        hist[t] = 0;
        __syncthreads();
        unsigned pref = sprefix;
        unsigned pmask = (round == 0) ? 0u : ~((1u << (shift + 8)) - 1u);
        for (int i = t; i < S_; i += 256) {
            unsigned u = su[i];
            if ((u & pmask) == (pref & pmask))
                atomicAdd(&hist[(u >> shift) & 255], 1);
        }
        __syncthreads();
        if (t == 0) {
            int rem = srem, run = 0;
            for (int v = 255; v >= 0; --v) {
                int h = hist[v];
                if (run + h >= rem) {
                    srem = rem - run;
                    sprefix = pref | ((unsigned)v << shift);
                    break;
                }
                run += h;
            }
        }
        __syncthreads();
    }
    unsigned T = sprefix;
    int need_eq = srem;

    int base = t * 16;
    int local_gt = 0, local_eq = 0;
    #pragma unroll
    for (int i = 0; i < 16; ++i) {
        unsigned u = su[base + i];
        local_gt += (u > T);
        local_eq += (u == T);
    }
    sg[t] = local_gt; se[t] = local_eq;
    __syncthreads();
    for (int o = 1; o < 256; o <<= 1) {
        int vg = (t >= o) ? sg[t - o] : 0;
        int ve = (t >= o) ? se[t - o] : 0;
        __syncthreads();
        sg[t] += vg; se[t] += ve;
        __syncthreads();
    }
    int gt_excl = sg[t] - local_gt;
    int eq_excl = se[t] - local_eq;
    int total_gt = sg[255];

    int gpos = gt_excl, epos = eq_excl;
    for (int i = 0; i < 16; ++i) {
        int s = base + i;
        unsigned u = su[s];
        int pos = -1;
        if (u > T) pos = gpos++;
        else if (u == T) { if (epos < need_eq) pos = total_gt + epos; epos++; }
        if (pos >= 0) {
            gidx[b * k + pos] = b * S_ + s;
            gwt[b * k + pos] = 1.f / (1.f + expf(-slog[s]));
        }
    }
}

// ---------------- gather selected rows -> packed bf16 A ----------------
__global__ void gather_k(const float* __restrict__ hidden, const int* __restrict__ gidx,
                         const int* __restrict__ kbuf, __hip_bfloat16* __restrict__ Ag) {
    int tid = blockIdx.x * 256 + threadIdx.x;  // B_*S_*(D_/4) worst case
    int m = tid >> 9, c4 = tid & 511;
    int M = B_ * kbuf[0];
    if (m >= M) return;
    int row = gidx[m];
    float4 v = ((const float4*)(hidden + (size_t)row * D_))[c4];
    ushort4 o;
    o.x = f2bf_bits(v.x); o.y = f2bf_bits(v.y); o.z = f2bf_bits(v.z); o.w = f2bf_bits(v.w);
    ((ushort4*)Ag)[tid] = o;
}

// ---------------- fp32 -> bf16 transpose (for B^T GEMM layout) ----------------
__global__ void transpose_cvt_k(const float* __restrict__ in, __hip_bfloat16* __restrict__ out,
                                int R, int C) {
    __shared__ float tile[32][33];
    int r0 = blockIdx.y * 32, c0 = blockIdx.x * 32;
    int tx = threadIdx.x, ty = threadIdx.y;
    #pragma unroll
    for (int i = 0; i < 32; i += 8)
        tile[ty + i][tx] = in[(size_t)(r0 + ty + i) * C + (c0 + tx)];
    __syncthreads();
    #pragma unroll
    for (int i = 0; i < 32; i += 8)
        out[(size_t)(c0 + ty + i) * R + (r0 + tx)] = __float2bfloat16(tile[tx][ty + i]);
}

// ---------------- GEMM1: H = gelu(Ag @ w1 + b1), bf16 MFMA ----------------
// grid: x = N-tile (fastest -> L2 reuse of A), y = M-tile
__global__ __launch_bounds__(256) void gemm1_k(const __hip_bfloat16* __restrict__ A,
                                               const __hip_bfloat16* __restrict__ BT,  // [DFF_][D_]
                                               const float* __restrict__ bias,
                                               __hip_bfloat16* __restrict__ H,
                                               const int* __restrict__ kbuf,
                                               int cBase, int CH) {
    int M = B_ * kbuf[0];
    int m0 = blockIdx.y * 128;
    if (m0 >= M) return;
    int nt = blockIdx.x;
    int n0g = cBase + nt * 128;
    __shared__ __align__(16) __hip_bfloat16 As[128 * 32];
    __shared__ __align__(16) __hip_bfloat16 Bs[128 * 32];
    int t = threadIdx.x;
    int lane = t & 63, wave = t >> 6;
    int wm = (wave & 1) * 64, wn = (wave >> 1) * 64;
    f32x4 acc[4][4] = {};

    int ar0 = t >> 2,            ac0 = (t & 3) * 8;
    int ar1 = (256 + t) >> 2,    ac1 = ((256 + t) & 3) * 8;
    int am0 = m0 + ar0; if (am0 >= M) am0 = M - 1;
    int am1 = m0 + ar1; if (am1 >= M) am1 = M - 1;
    const __hip_bfloat16* aP0 = A + (size_t)am0 * D_ + ac0;
    const __hip_bfloat16* aP1 = A + (size_t)am1 * D_ + ac1;
    const __hip_bfloat16* bP0 = BT + (size_t)(n0g + ar0) * D_ + ac0;
    const __hip_bfloat16* bP1 = BT + (size_t)(n0g + ar1) * D_ + ac1;
    unsigned ldsOff0 = (unsigned)(wave * 64) * 16u;
    unsigned ldsOff1 = 4096u + (unsigned)(wave * 64) * 16u;

    for (int kk = 0; kk < D_; kk += 32) {
        GLD16(aP0 + kk, (char*)As + ldsOff0);
        GLD16(aP1 + kk, (char*)As + ldsOff1);
        GLD16(bP0 + kk, (char*)Bs + ldsOff0);
        GLD16(bP1 + kk, (char*)Bs + ldsOff1);
        __syncthreads();
        bf16x8 af[4], bfr[4];
        #pragma unroll
        for (int i = 0; i < 4; ++i)
            af[i] = *(const bf16x8*)(As + (wm + i * 16 + (lane & 15)) * 32 + (lane >> 4) * 8);
        #pragma unroll
        for (int j = 0; j < 4; ++j)
            bfr[j] = *(const bf16x8*)(Bs + (wn + j * 16 + (lane & 15)) * 32 + (lane >> 4) * 8);
        #pragma unroll
        for (int i = 0; i < 4; ++i)
            #pragma unroll
            for (int j = 0; j < 4; ++j)
                acc[i][j] = __builtin_amdgcn_mfma_f32_16x16x32_bf16(af[i], bfr[j], acc[i][j], 0, 0, 0);
        __syncthreads();
    }

    int qrow = (lane >> 4) * 4, qcol = lane & 15;
    #pragma unroll
    for (int i = 0; i < 4; ++i) {
        #pragma unroll
        for (int j = 0; j < 4; ++j) {
            int cc = wn + j * 16 + qcol;
            float bv = bias[n0g + cc];
            #pragma unroll
            for (int r = 0; r < 4; ++r) {
                int mm = m0 + wm + i * 16 + qrow + r;
                if (mm < M) {
                    float v = acc[i][j][r] + bv;
                    H[(size_t)mm * CH + (nt * 128 + cc)] = __float2bfloat16(gelu_exact(v));
                }
            }
        }
    }
}

// ---------------- GEMM2: out[gidx[m]] += gwt[m] * (H @ w2 + b2) ----------------
// grid: x = N-tile (fastest), y = M-tile
__global__ __launch_bounds__(256) void gemm2_k(const __hip_bfloat16* __restrict__ A,   // H [*][CH]
                                               const __hip_bfloat16* __restrict__ BT,  // [D_][DFF_]
                                               const float* __restrict__ bias,
                                               const int* __restrict__ gidx,
                                               const float* __restrict__ gwt,
                                               float* __restrict__ out,
                                               const int* __restrict__ kbuf,
                                               int cBase, int CH, int first) {
    int M = B_ * kbuf[0];
    int m0 = blockIdx.y * 128;
    if (m0 >= M) return;
    int nt = blockIdx.x;
    int n0 = nt * 128;
    __shared__ __align__(16) __hip_bfloat16 As[128 * 32];
    __shared__ __align__(16) __hip_bfloat16 Bs[128 * 32];
    int t = threadIdx.x;
    int lane = t & 63, wave = t >> 6;
    int wm = (wave & 1) * 64, wn = (wave >> 1) * 64;
    f32x4 acc[4][4] = {};

    int ar0 = t >> 2,            ac0 = (t & 3) * 8;
    int ar1 = (256 + t) >> 2,    ac1 = ((256 + t) & 3) * 8;
    int am0 = m0 + ar0; if (am0 >= M) am0 = M - 1;
    int am1 = m0 + ar1; if (am1 >= M) am1 = M - 1;
    const __hip_bfloat16* aP0 = A + (size_t)am0 * CH + ac0;
    const __hip_bfloat16* aP1 = A + (size_t)am1 * CH + ac1;
    const __hip_bfloat16* bP0 = BT + (size_t)(n0 + ar0) * DFF_ + cBase + ac0;
    const __hip_bfloat16* bP1 = BT + (size_t)(n0 + ar1) * DFF_ + cBase + ac1;
    unsigned ldsOff0 = (unsigned)(wave * 64) * 16u;
    unsigned ldsOff1 = 4096u + (unsigned)(wave * 64) * 16u;

    for (int kk = 0; kk < CH; kk += 32) {
        GLD16(aP0 + kk, (char*)As + ldsOff0);
        GLD16(aP1 + kk, (char*)As + ldsOff1);
        GLD16(bP0 + kk, (char*)Bs + ldsOff0);
        GLD16(bP1 + kk, (char*)Bs + ldsOff1);
        __syncthreads();
        bf16x8 af[4], bfr[4];
        #pragma unroll
        for (int i = 0; i < 4; ++i)
            af[i] = *(const bf16x8*)(As + (wm + i * 16 + (lane & 15)) * 32 + (lane >> 4) * 8);
        #pragma unroll
        for (int j = 0; j < 4; ++j)
            bfr[j] = *(const bf16x8*)(Bs + (wn + j * 16 + (lane & 15)) * 32 + (lane >> 4) * 8);
        #pragma unroll
        for (int i = 0; i < 4; ++i)
            #pragma unroll
            for (int j = 0; j < 4; ++j)
                acc[i][j] = __builtin_amdgcn_mfma_f32_16x16x32_bf16(af[i], bfr[j], acc[i][j], 0, 0, 0);
        __syncthreads();
    }

    int qrow = (lane >> 4) * 4, qcol = lane & 15;
    #pragma unroll
    for (int i = 0; i < 4; ++i) {
        #pragma unroll
        for (int j = 0; j < 4; ++j) {
            int cc = wn + j * 16 + qcol;
            int nglob = n0 + cc;
            float bv = bias[nglob];
            #pragma unroll
            for (int r = 0; r < 4; ++r) {
                int mm = m0 + wm + i * 16 + qrow + r;
                if (mm < M) {
                    int grow = gidx[mm];
                    float wgt = gwt[mm];
                    float v = acc[i][j][r];
                    if (first) v += bv;
                    out[(size_t)grow * D_ + nglob] += wgt * v;
                }
            }
        }
    }
}

extern "C" void kernel_launch(void* const* d_in, const int* in_sizes, int n_in,
                              void* d_out, int out_size, void* d_ws, size_t ws_size,
                              hipStream_t stream) {
    (void)in_sizes; (void)n_in;
    const float* hidden = (const float*)d_in[0];
    const float* rw  = (const float*)d_in[1];
    const float* rb  = (const float*)d_in[2];
    const float* cw1 = (const float*)d_in[3];
    const float* cb1 = (const float*)d_in[4];
    const float* cw2 = (const float*)d_in[5];
    const float* cb2 = (const float*)d_in[6];
    const float* fw1 = (const float*)d_in[7];
    const float* fb1 = (const float*)d_in[8];
    const float* fw2 = (const float*)d_in[9];
    const float* fb2 = (const float*)d_in[10];

    char* ws = (char*)d_ws;
    size_t off = 0;
    auto alloc = [&](size_t bytes) {
        size_t r = (off + 255) & ~(size_t)255;
        off = r + bytes;
        return r;
    };
    size_t o_logits = alloc((size_t)B_ * S_ * 4);
    size_t o_pp     = alloc((size_t)8 * B_ * D_ * 4);
    size_t o_pooled = alloc((size_t)B_ * D_ * 4);
    size_t o_ch     = alloc((size_t)B_ * DC_ * 4);
    size_t o_k      = alloc(256);
    size_t o_gidx   = alloc((size_t)B_ * S_ * 4);
    size_t o_gwt    = alloc((size_t)B_ * S_ * 4);
    size_t o_w1T    = alloc((size_t)D_ * DFF_ * 2);
    size_t o_w2T    = alloc((size_t)D_ * DFF_ * 2);
    size_t o_Ag     = alloc((size_t)B_ * S_ * D_ * 2);
    size_t base     = (off + 255) & ~(size_t)255;
    int CH = DFF_;
    while (CH > 128 && base + (size_t)B_ * S_ * CH * 2 > ws_size) CH >>= 1;
    size_t o_H = alloc((size_t)B_ * S_ * CH * 2);

    float* logits = (float*)(ws + o_logits);
    float* pp     = (float*)(ws + o_pp);
    float* pooled = (float*)(ws + o_pooled);
    float* ch     = (float*)(ws + o_ch);
    int*   kbuf   = (int*)(ws + o_k);
    int*   gidx   = (int*)(ws + o_gidx);
    float* gwt    = (float*)(ws + o_gwt);
    __hip_bfloat16* w1T = (__hip_bfloat16*)(ws + o_w1T);
    __hip_bfloat16* w2T = (__hip_bfloat16*)(ws + o_w2T);
    __hip_bfloat16* Ag  = (__hip_bfloat16*)(ws + o_Ag);
    __hip_bfloat16* H   = (__hip_bfloat16*)(ws + o_H);
    float* out = (float*)d_out;

    pool_partial_k<<<dim3(D_ / 256, 8, B_), 256, 0, stream>>>(hidden, pp);
    pool_reduce_k<<<dim3(B_ * D_ / 256), 256, 0, stream>>>(pp, pooled);
    logits_k<<<dim3(B_ * S_ / 4), 256, 0, stream>>>(hidden, rw, rb, logits);
    head1_k<<<dim3(B_ * DC_ / 256), 256, 0, stream>>>(pooled, cw1, cb1, ch);
    head2_k<<<dim3(1), 256, 0, stream>>>(ch, cw2, cb2, kbuf);
    select_k<<<dim3(B_), 256, 0, stream>>>(logits, kbuf, gidx, gwt);
    gather_k<<<dim3(B_ * S_ * (D_ / 4) / 256), 256, 0, stream>>>(hidden, gidx, kbuf, Ag);
    transpose_cvt_k<<<dim3(DFF_ / 32, D_ / 32), dim3(32, 8), 0, stream>>>(fw1, w1T, D_, DFF_);
    transpose_cvt_k<<<dim3(D_ / 32, DFF_ / 32), dim3(32, 8), 0, stream>>>(fw2, w2T, DFF_, D_);
    hipMemcpyAsync(d_out, (const void*)hidden, (size_t)out_size * 4,
                   hipMemcpyDeviceToDevice, stream);

    int nch = DFF_ / CH;
    for (int c = 0; c < nch; ++c) {
        gemm1_k<<<dim3(CH / 128, B_ * S_ / 128), 256, 0, stream>>>(
            Ag, w1T, fb1, H, kbuf, c * CH, CH);
        gemm2_k<<<dim3(D_ / 128, B_ * S_ / 128), 256, 0, stream>>>(
            H, w2T, fb2, gidx, gwt, out, kbuf, c * CH, CH, c == 0);
    }
}